// Round 6
// baseline (180.014 us; speedup 1.0000x reference)
//
#include <hip/hip_runtime.h>
#include <hip/hip_bf16.h>
#include <cstdint>

typedef __bf16 bf16x8 __attribute__((ext_vector_type(8)));
typedef __bf16 bf16x2 __attribute__((ext_vector_type(2)));
typedef float f32x4 __attribute__((ext_vector_type(4)));
typedef float f32x2 __attribute__((ext_vector_type(2)));

#define E_DIM 256
#define H_DIM 512
#define PST 516   // padded LDS slab row stride (f32): 516*4 B, 16B-aligned, breaks bank aliasing

// packed f32x2 -> bf16x2 (RNE): lowers to v_cvt_pk_bf16_f32 on gfx950
static __device__ __forceinline__ unsigned pkbf(float a, float b) {
    bf16x2 h;
    h[0] = (__bf16)a;
    h[1] = (__bf16)b;
    return __builtin_bit_cast(unsigned, h);
}

// async global->LDS DMA, 16 B/lane: LDS dest = uniform base + lane*16
static __device__ __forceinline__ void gl_lds16(const float* g, float* l) {
    __builtin_amdgcn_global_load_lds(
        (const __attribute__((address_space(1))) void*)g,
        (__attribute__((address_space(3))) void*)l, 16, 0, 0);
}

// ---------------- kernel 1: fused prep (unchanged) ----------------
// blocks 0..255  : P = norm(t)@W1a + b1 ; Q = norm(d)@W1b (MFMA, inline f32->bf16 W conv)
// blocks 256..287: convert W1c (mat 2) to bf16 chunk-major [c][h][kk] for main.
// blocks 288..303: zero 'out' so main can accumulate partials via global atomics.
__global__ __launch_bounds__(512, 2)
void prep_kernel(const float* __restrict__ track, const float* __restrict__ det,
                 const float* __restrict__ W1, const float* __restrict__ b1,
                 float* __restrict__ P, float* __restrict__ Q,
                 __bf16* __restrict__ W1cc, float* __restrict__ sclT,
                 float* __restrict__ sclD, float* __restrict__ out) {
    __shared__ __align__(16) __bf16 Ash[16 * 256];   // 8 KB
    int tid = threadIdx.x;
    int blk = blockIdx.x;

    if (blk >= 288) {
        int u = (blk - 288) * 512 + tid;
        float4 z = {0.f, 0.f, 0.f, 0.f};
#pragma unroll
        for (int i = 0; i < 4; ++i)
            ((float4*)out)[u + 8192 * i] = z;
        return;
    }
    if (blk >= 256) {
        int u = (blk - 256) * 512 + tid;
        int j = u & 3;
        int h = (u >> 2) & 511;
        int c = u >> 11;                              // 0..7
        const float* src = W1 + (size_t)(512 + c * 32 + j * 8) * H_DIM + h;
        uint4 v;
        v.x = pkbf(src[0],                 src[(size_t)1 * H_DIM]);
        v.y = pkbf(src[(size_t)2 * H_DIM], src[(size_t)3 * H_DIM]);
        v.z = pkbf(src[(size_t)4 * H_DIM], src[(size_t)5 * H_DIM]);
        v.w = pkbf(src[(size_t)6 * H_DIM], src[(size_t)7 * H_DIM]);
        *(uint4*)(W1cc + ((size_t)(c * 512 + h) * 32 + j * 8)) = v;
        return;
    }

    int lane = tid & 63;
    int wave = tid >> 6;
    int lq   = lane >> 4;
    int lc   = lane & 15;
    int l5   = lane & 31;

    int mat  = blk >> 7;               // 0 = P(track), 1 = Q(det)
    int rowg = (blk >> 1) & 63;
    int half = blk & 1;
    int r0   = rowg * 16;
    int h0   = half * 256;
    const float* src = mat ? det : track;

    {
        int row = wave * 2 + (lane >> 5);           // 0..15
        const float* gp = src + (size_t)(r0 + row) * E_DIM + l5 * 8;
        float4 x0 = *(const float4*)gp;
        float4 x1 = *(const float4*)(gp + 4);
        float ss = x0.x*x0.x + x0.y*x0.y + x0.z*x0.z + x0.w*x0.w
                 + x1.x*x1.x + x1.y*x1.y + x1.z*x1.z + x1.w*x1.w;
#pragma unroll
        for (int off = 16; off > 0; off >>= 1) ss += __shfl_xor(ss, off);   // 32-lane groups
        float st = 1.0f / fmaxf(sqrtf(ss), 1e-12f);
        if (half == 0 && l5 == 0) (mat ? sclD : sclT)[r0 + row] = st;
        uint4 v;
        v.x = pkbf(x0.x * st, x0.y * st);
        v.y = pkbf(x0.z * st, x0.w * st);
        v.z = pkbf(x1.x * st, x1.y * st);
        v.w = pkbf(x1.z * st, x1.w * st);
        int cc = l5 >> 2, j = l5 & 3;               // chunk, k-subgroup
        *(uint4*)&Ash[(size_t)(cc * 64 + j * 16 + row) * 8] = v;
    }
    __syncthreads();

    int hB = h0 + wave * 32 + lc;
    const float* wb = W1 + (size_t)(mat * 256) * H_DIM + hB;
    float wf[2][8];
#pragma unroll
    for (int ht = 0; ht < 2; ++ht)
#pragma unroll
        for (int i = 0; i < 8; ++i)
            wf[ht][i] = wb[(size_t)(lq * 8 + i) * H_DIM + ht * 16];

    f32x4 acc[2];
    acc[0] = (f32x4){0.f, 0.f, 0.f, 0.f};
    acc[1] = (f32x4){0.f, 0.f, 0.f, 0.f};

#pragma unroll
    for (int c = 0; c < 8; ++c) {
        bf16x8 cw[2];
#pragma unroll
        for (int ht = 0; ht < 2; ++ht) {
            uint4 u;
            u.x = pkbf(wf[ht][0], wf[ht][1]);
            u.y = pkbf(wf[ht][2], wf[ht][3]);
            u.z = pkbf(wf[ht][4], wf[ht][5]);
            u.w = pkbf(wf[ht][6], wf[ht][7]);
            cw[ht] = __builtin_bit_cast(bf16x8, u);
        }
        if (c < 7) {
            const float* nb = wb + (size_t)((c + 1) * 32 + lq * 8) * H_DIM;
#pragma unroll
            for (int ht = 0; ht < 2; ++ht)
#pragma unroll
                for (int i = 0; i < 8; ++i)
                    wf[ht][i] = nb[(size_t)i * H_DIM + ht * 16];
        }
        bf16x8 af = *(const bf16x8*)&Ash[(size_t)(c * 64 + lane) * 8];
#pragma unroll
        for (int ht = 0; ht < 2; ++ht)
            acc[ht] = __builtin_amdgcn_mfma_f32_16x16x32_bf16(cw[ht], af, acc[ht], 0, 0, 0);
    }

    float* dst = mat ? Q : P;
#pragma unroll
    for (int ht = 0; ht < 2; ++ht) {
        int h = h0 + wave * 32 + ht * 16 + lq * 4;
        f32x4 o = acc[ht];
        if (!mat) o += *(const f32x4*)&b1[h];
        *(f32x4*)&dst[(size_t)(r0 + lc) * H_DIM + h] = o;
    }
}

// ---------------- kernel 2: persistent fused pairwise GEMM + LN + SiLU + W2 dot ----------------
// grid 512 x 512 thr = exactly 2 blocks/CU, resident for the whole kernel.
// Block owns (batch, n-tile) and loops over 4 consecutive m-tiles:
//   - P slab (8 n-rows x 512 h) loaded to LDS ONCE via async global_load_lds.
//   - Q slab for tile j+1 DMA-prefetched into LDS right after tile j's C-init
//     consumes it (fenced by vmcnt(0) before the stats barrier — free by then).
//   - W ping-pong naturally prefetches chunk 0 of tile j+1 during tile j's last chunk.
// XCD swizzle: XCD x owns a 4n x 8m tile region per batch (hot set ~2.5 MB < 4 MB L2).
__global__ __launch_bounds__(512, 4)
void main_kernel(const float* __restrict__ track, const float* __restrict__ det,
                 const __bf16* __restrict__ W1cc,
                 const float* __restrict__ P, const float* __restrict__ Q,
                 const float* __restrict__ sclT, const float* __restrict__ sclD,
                 const float* __restrict__ gamma, const float* __restrict__ beta,
                 const float* __restrict__ W2, const float* __restrict__ b2,
                 float* __restrict__ out) {
    __shared__ __align__(16) char SMEM[77056];
    __bf16* Ash  = (__bf16*)SMEM;                     // [0,32768)
    float*  LNr1 = (float*)(SMEM + 32768);            // [64][9]
    float*  LNr2 = (float*)(SMEM + 35072);            // [64][9]
    float*  AS   = (float*)(SMEM + 37376);            // [64]  a = rs
    float*  BS   = (float*)(SMEM + 37632);            // [64]  b = -mu*rs
    float*  Gs   = (float*)(SMEM + 37888);            // [512]
    float*  Bs   = (float*)(SMEM + 39936);            // [512]
    float*  Ws   = (float*)(SMEM + 41984);            // [512]
    float*  Psh  = (float*)(SMEM + 44032);            // [8][PST]
    float*  Qsh  = (float*)(SMEM + 60544);            // [8][PST]

    int tid  = threadIdx.x;
    int lane = tid & 63;
    int wave = tid >> 6;
    int lq   = lane >> 4;
    int lc   = lane & 15;
    int ml   = lane & 7;

    // persistent-block tile assignment + XCD swizzle
    int id  = blockIdx.x;              // 0..511
    int xcd = id & 7;
    int u   = id >> 3;                 // 0..63
    int b   = u >> 3;                  // 0..7
    int v   = u & 7;
    int gn  = b * 128 + ((xcd >> 1) * 4 + (v >> 1)) * 8;   // fixed n-rows
    int mtb = (xcd & 1) * 8 + (v & 1) * 4;                 // 4 consecutive m-tiles

    float b2v = b2[0];
    Gs[tid] = gamma[tid];
    Bs[tid] = beta[tid];
    Ws[tid] = W2[tid];

    // ---- async P slab + tile-0 Q slab -> LDS (wave w owns row w, 2x 1KB DMAs each)
    {
        const float* gp = P + (size_t)(gn + wave) * H_DIM + lane * 4;
        gl_lds16(gp,       Psh + wave * PST);
        gl_lds16(gp + 256, Psh + wave * PST + 256);
        int gm0 = b * 128 + mtb * 8;
        const float* gq = Q + (size_t)(gm0 + wave) * H_DIM + lane * 4;
        gl_lds16(gq,       Qsh + wave * PST);
        gl_lds16(gq + 256, Qsh + wave * PST + 256);
    }

    // ---- W1c chunk-0 prefetch (ping-pong carries chunk-0 across tiles afterwards)
    const uint4* Wg = (const uint4*)W1cc;
    int hb = wave * 64 + lc;
    bf16x8 bwA[4], bwB[4];
#pragma unroll
    for (int ht = 0; ht < 4; ++ht)
        bwA[ht] = __builtin_bit_cast(bf16x8, Wg[(hb + ht * 16) * 4 + lq]);

    // ---- t-row scales: constant across the 4 tiles
    float stv[4];
#pragma unroll
    for (int r = 0; r < 4; ++r)
        stv[r] = sclT[gn + r * 2 + (lc >> 3)];

    asm volatile("s_waitcnt vmcnt(0)" ::: "memory");
    __syncthreads();                                   // Psh/Qsh(0) resident

    for (int j = 0; j < 4; ++j) {
        int gm = b * 128 + (mtb + j) * 8;

        // ---- A-stage: |t*st - d*sd| from global (t L1-hot across tiles) -> Ash
        {
            int k0 = wave * 32 + lq * 8;
            float sd = sclD[gm + ml];
            const float* dr = det + (size_t)(gm + ml) * E_DIM + k0;
            float4 d0 = *(const float4*)dr;
            float4 d1 = *(const float4*)(dr + 4);
#pragma unroll
            for (int r = 0; r < 4; ++r) {
                int nl = r * 2 + (lc >> 3);
                float st = stv[r];
                const float* tr = track + (size_t)(gn + nl) * E_DIM + k0;
                float4 t0 = *(const float4*)tr;
                float4 t1 = *(const float4*)(tr + 4);
                uint4 w;
                w.x = pkbf(fabsf(t0.x * st - d0.x * sd), fabsf(t0.y * st - d0.y * sd));
                w.y = pkbf(fabsf(t0.z * st - d0.z * sd), fabsf(t0.w * st - d0.w * sd));
                w.z = pkbf(fabsf(t1.x * st - d1.x * sd), fabsf(t1.y * st - d1.y * sd));
                w.w = pkbf(fabsf(t1.z * st - d1.z * sd), fabsf(t1.w * st - d1.w * sd));
                *(uint4*)&Ash[(size_t)(r * 512 + wave * 64 + lane) * 8] = w;
            }
        }

        // ---- C-init from LDS: acc = Psh[n,h] + Qsh[m,h]
        f32x4 acc[4][4];
        {
            f32x4 qv[4];
#pragma unroll
            for (int ht = 0; ht < 4; ++ht)
                qv[ht] = *(const f32x4*)&Qsh[ml * PST + wave * 64 + ht * 16 + lq * 4];
#pragma unroll
            for (int pt = 0; pt < 4; ++pt) {
                int n = pt * 2 + (lc >> 3);
#pragma unroll
                for (int ht = 0; ht < 4; ++ht) {
                    f32x4 pv = *(const f32x4*)&Psh[n * PST + wave * 64 + ht * 16 + lq * 4];
                    acc[pt][ht] = pv + qv[ht];
                }
            }
        }
        __syncthreads();                               // B1: Ash ready, Qsh consumed

        // ---- DMA-prefetch next tile's Q slab (hides under the whole K-loop)
        if (j < 3) {
            int gmn = b * 128 + (mtb + j + 1) * 8;
            const float* gq = Q + (size_t)(gmn + wave) * H_DIM + lane * 4;
            gl_lds16(gq,       Qsh + wave * PST);
            gl_lds16(gq + 256, Qsh + wave * PST + 256);
        }

        // ---- K-loop: zero barriers; unroll-2 ping-pong dbuf; setprio around MFMA
#pragma unroll 2
        for (int c = 0; c < 8; ++c) {
            bf16x8* cur = (c & 1) ? bwB : bwA;
            bf16x8* nxt = (c & 1) ? bwA : bwB;
            int c1 = (c + 1) & 7;
#pragma unroll
            for (int ht = 0; ht < 4; ++ht)
                nxt[ht] = __builtin_bit_cast(bf16x8, Wg[c1 * 2048 + (hb + ht * 16) * 4 + lq]);
            __builtin_amdgcn_s_setprio(1);
#pragma unroll
            for (int pt = 0; pt < 4; ++pt) {
                bf16x8 af = *(const bf16x8*)&Ash[(size_t)((pt * 8 + c) * 64 + lane) * 8];
#pragma unroll
                for (int ht = 0; ht < 4; ++ht)
                    acc[pt][ht] = __builtin_amdgcn_mfma_f32_16x16x32_bf16(cur[ht], af, acc[pt][ht], 0, 0, 0);
            }
            __builtin_amdgcn_s_setprio(0);
        }

        // ---- LN partials: packed f32x2 sums, 2 shuffles, two-stage LDS reduce
#pragma unroll
        for (int pt = 0; pt < 4; ++pt) {
            f32x2 s1v = (f32x2){0.f, 0.f}, s2v = (f32x2){0.f, 0.f};
#pragma unroll
            for (int ht = 0; ht < 4; ++ht) {
#pragma unroll
                for (int hf = 0; hf < 2; ++hf) {
                    f32x2 vv = (f32x2){acc[pt][ht][hf * 2], acc[pt][ht][hf * 2 + 1]};
                    s1v += vv;
                    s2v += vv * vv;
                }
            }
            float s1 = s1v[0] + s1v[1];
            float s2 = s2v[0] + s2v[1];
            s1 += __shfl_xor(s1, 16); s2 += __shfl_xor(s2, 16);
            s1 += __shfl_xor(s1, 32); s2 += __shfl_xor(s2, 32);
            if (lq == 0) {
                LNr1[(pt * 16 + lc) * 9 + wave] = s1;
                LNr2[(pt * 16 + lc) * 9 + wave] = s2;
            }
        }
        __syncthreads();                               // B2
        {
            int p = tid >> 3, w = tid & 7;
            float s1 = LNr1[p * 9 + w];
            float s2 = LNr2[p * 9 + w];
            s1 += __shfl_xor(s1, 1); s2 += __shfl_xor(s2, 1);
            s1 += __shfl_xor(s1, 2); s2 += __shfl_xor(s2, 2);
            s1 += __shfl_xor(s1, 4); s2 += __shfl_xor(s2, 4);
            if (w == 0) {
                float mu  = s1 * (1.0f / 512.0f);
                float var = s2 * (1.0f / 512.0f) - mu * mu;
                float rs  = rsqrtf(var + 1e-5f);
                AS[p] = rs;
                BS[p] = -mu * rs;
            }
        }
        asm volatile("s_waitcnt vmcnt(0)" ::: "memory");  // Q_{j+1} DMA landed (free by now)
        __syncthreads();                               // B3: AS/BS + Qsh_{j+1} visible

        // ---- epilogue: x = (v*a + b)*g + beta; SiLU; W2 dot; packed f32x2 chain
        float as[4], bs[4];
#pragma unroll
        for (int pt = 0; pt < 4; ++pt) { as[pt] = AS[pt * 16 + lc]; bs[pt] = BS[pt * 16 + lc]; }
        f32x2 cav[4];
#pragma unroll
        for (int pt = 0; pt < 4; ++pt) cav[pt] = (f32x2){0.f, 0.f};
#pragma unroll
        for (int ht = 0; ht < 4; ++ht) {
            int h = wave * 64 + ht * 16 + lq * 4;
            f32x4 g  = *(const f32x4*)&Gs[h];
            f32x4 bb = *(const f32x4*)&Bs[h];
            f32x4 w  = *(const f32x4*)&Ws[h];
#pragma unroll
            for (int pt = 0; pt < 4; ++pt) {
                f32x2 a2  = (f32x2){as[pt], as[pt]};
                f32x2 b2p = (f32x2){bs[pt], bs[pt]};
#pragma unroll
                for (int hf = 0; hf < 2; ++hf) {
                    f32x2 vv = (f32x2){acc[pt][ht][hf * 2], acc[pt][ht][hf * 2 + 1]};
                    f32x2 gg = (f32x2){g[hf * 2],  g[hf * 2 + 1]};
                    f32x2 bv = (f32x2){bb[hf * 2], bb[hf * 2 + 1]};
                    f32x2 wv = (f32x2){w[hf * 2],  w[hf * 2 + 1]};
                    f32x2 x  = (vv * a2 + b2p) * gg + bv;
                    f32x2 xw = x * wv;
                    f32x2 e, sg;
                    e[0]  = __expf(-x[0]);
                    e[1]  = __expf(-x[1]);
                    sg[0] = __builtin_amdgcn_rcpf(1.0f + e[0]);
                    sg[1] = __builtin_amdgcn_rcpf(1.0f + e[1]);
                    cav[pt] += xw * sg;
                }
            }
        }
        // ---- output: per-wave partial -> fire-and-forget global atomic
#pragma unroll
        for (int pt = 0; pt < 4; ++pt) {
            float cg = cav[pt][0] + cav[pt][1];
            cg += __shfl_xor(cg, 16);
            cg += __shfl_xor(cg, 32);
            if (lq == 0) {
                if (wave == 0) cg += b2v;              // fold bias exactly once
                int n = pt * 2 + (lc >> 3);
                int m = lc & 7;
                atomicAdd(&out[(size_t)(gn + n) * 128 + (mtb + j) * 8 + m], cg);
            }
        }
    }
}

extern "C" void kernel_launch(void* const* d_in, const int* in_sizes, int n_in,
                              void* d_out, int out_size, void* d_ws, size_t ws_size,
                              hipStream_t stream) {
    const float* track = (const float*)d_in[0];
    const float* det   = (const float*)d_in[1];
    const float* W1    = (const float*)d_in[2];
    const float* b1    = (const float*)d_in[3];
    const float* gamma = (const float*)d_in[4];
    const float* beta  = (const float*)d_in[5];
    const float* W2    = (const float*)d_in[6];
    const float* b2    = (const float*)d_in[7];
    float* out = (float*)d_out;

    char* ws = (char*)d_ws;
    float*  Pp   = (float*)(ws);                              // 2 MB (1024 x 512 f32)
    float*  Qp   = (float*)(ws + (2u << 20));                 // 2 MB
    __bf16* W1cc = (__bf16*)(ws + (4u << 20));                // 256 KB (mat 2 only)
    float*  sclT = (float*)(ws + (4u << 20) + (256u << 10));  // 4 KB
    float*  sclD = (float*)(ws + (4u << 20) + (264u << 10));  // 4 KB

    prep_kernel<<<304, 512, 0, stream>>>(track, det, W1, b1, Pp, Qp, W1cc, sclT, sclD, out);
    main_kernel<<<512, 512, 0, stream>>>(track, det, W1cc, Pp, Qp, sclT, sclD,
                                         gamma, beta, W2, b2, out);
}

// Round 7
// 141.922 us; speedup vs baseline: 1.2684x; 1.2684x over previous
//
#include <hip/hip_runtime.h>
#include <hip/hip_bf16.h>
#include <cstdint>

typedef __bf16 bf16x8 __attribute__((ext_vector_type(8)));
typedef __bf16 bf16x2 __attribute__((ext_vector_type(2)));
typedef float f32x4 __attribute__((ext_vector_type(4)));
typedef float f32x2 __attribute__((ext_vector_type(2)));

#define E_DIM 256
#define H_DIM 512

// packed f32x2 -> bf16x2 (RNE): lowers to v_cvt_pk_bf16_f32 on gfx950
static __device__ __forceinline__ unsigned pkbf(float a, float b) {
    bf16x2 h;
    h[0] = (__bf16)a;
    h[1] = (__bf16)b;
    return __builtin_bit_cast(unsigned, h);
}

// ---------------- kernel 1: fused prep, v2 ----------------
// 512 uniform blocks = (mat 2) x (rowgroup-of-16 64) x (h-quarter 4).
// Each block: [prologue: 32 uint4 of W1c->bf16 conv (threads 0-31) + 64 float4
// of out-zeroing (threads 32-95), overlapped with row-load+norm] -> barrier ->
// 8-chunk K-loop with ONE 16-h W fragment per wave (8 scattered loads/thread/chunk,
// depth-1 prefetch, inline f32->bf16 cvt) -> 1 MFMA/chunk -> store P/Q slice.
// vs v1 (256 fat blocks + 48 aux): 2x occupancy during the latency-bound W gather,
// half the per-thread load count, single dispatch generation.
__global__ __launch_bounds__(512, 2)
void prep_kernel(const float* __restrict__ track, const float* __restrict__ det,
                 const float* __restrict__ W1, const float* __restrict__ b1,
                 float* __restrict__ P, float* __restrict__ Q,
                 __bf16* __restrict__ W1cc, float* __restrict__ sclT,
                 float* __restrict__ sclD, float* __restrict__ out) {
    __shared__ __align__(16) __bf16 Ash[16 * 256];   // 8 KB
    int tid  = threadIdx.x;
    int blk  = blockIdx.x;            // 0..511
    int lane = tid & 63;
    int wave = tid >> 6;
    int lq   = lane >> 4;
    int lc   = lane & 15;
    int l5   = lane & 31;

    int mat  = blk >> 8;              // 0 = P(track), 1 = Q(det)
    int rowg = (blk >> 2) & 63;
    int hq   = blk & 3;
    int r0   = rowg * 16;
    int h0   = hq * 128;
    const float* src = mat ? det : track;

    // ---- scattered side jobs (before barrier; overlap with norm phase)
    if (tid < 32) {
        // W1c -> bf16 chunk-major: 32 of 16384 uint4 per block
        int u = blk * 32 + tid;
        int j = u & 3;
        int h = (u >> 2) & 511;
        int c = u >> 11;                              // 0..7
        const float* s = W1 + (size_t)(512 + c * 32 + j * 8) * H_DIM + h;
        uint4 v;
        v.x = pkbf(s[0],                 s[(size_t)1 * H_DIM]);
        v.y = pkbf(s[(size_t)2 * H_DIM], s[(size_t)3 * H_DIM]);
        v.z = pkbf(s[(size_t)4 * H_DIM], s[(size_t)5 * H_DIM]);
        v.w = pkbf(s[(size_t)6 * H_DIM], s[(size_t)7 * H_DIM]);
        *(uint4*)(W1cc + ((size_t)(c * 512 + h) * 32 + j * 8)) = v;
    } else if (tid < 96) {
        // zero 'out' for main's global-atomic accumulation: 64 float4 per block
        float4 z = {0.f, 0.f, 0.f, 0.f};
        ((float4*)out)[blk * 64 + (tid - 32)] = z;
    }

    // ---- load 2 rows per wave, normalize in-register, write Ash (chunk-major) + scales
    {
        int row = wave * 2 + (lane >> 5);           // 0..15
        const float* gp = src + (size_t)(r0 + row) * E_DIM + l5 * 8;
        float4 x0 = *(const float4*)gp;
        float4 x1 = *(const float4*)(gp + 4);
        float ss = x0.x*x0.x + x0.y*x0.y + x0.z*x0.z + x0.w*x0.w
                 + x1.x*x1.x + x1.y*x1.y + x1.z*x1.z + x1.w*x1.w;
#pragma unroll
        for (int off = 16; off > 0; off >>= 1) ss += __shfl_xor(ss, off);   // 32-lane groups
        float st = 1.0f / fmaxf(sqrtf(ss), 1e-12f);
        if (hq == 0 && l5 == 0) (mat ? sclD : sclT)[r0 + row] = st;
        uint4 v;
        v.x = pkbf(x0.x * st, x0.y * st);
        v.y = pkbf(x0.z * st, x0.w * st);
        v.z = pkbf(x1.x * st, x1.y * st);
        v.w = pkbf(x1.z * st, x1.w * st);
        int cc = l5 >> 2, j = l5 & 3;               // chunk, k-subgroup
        *(uint4*)&Ash[(size_t)(cc * 64 + j * 16 + row) * 8] = v;
    }
    __syncthreads();

    // ---- K-loop: one 16-h W fragment per wave, gathered f32 from L2, cvt inline
    int hB = h0 + wave * 16 + lc;
    const float* wb = W1 + (size_t)(mat * 256) * H_DIM + hB;
    float wf[8];
#pragma unroll
    for (int i = 0; i < 8; ++i)
        wf[i] = wb[(size_t)(lq * 8 + i) * H_DIM];

    f32x4 acc = (f32x4){0.f, 0.f, 0.f, 0.f};

#pragma unroll
    for (int c = 0; c < 8; ++c) {
        uint4 u;
        u.x = pkbf(wf[0], wf[1]);
        u.y = pkbf(wf[2], wf[3]);
        u.z = pkbf(wf[4], wf[5]);
        u.w = pkbf(wf[6], wf[7]);
        bf16x8 cw = __builtin_bit_cast(bf16x8, u);
        if (c < 7) {
            const float* nb = wb + (size_t)((c + 1) * 32 + lq * 8) * H_DIM;
#pragma unroll
            for (int i = 0; i < 8; ++i)
                wf[i] = nb[(size_t)i * H_DIM];
        }
        bf16x8 af = *(const bf16x8*)&Ash[(size_t)(c * 64 + lane) * 8];
        acc = __builtin_amdgcn_mfma_f32_16x16x32_bf16(cw, af, acc, 0, 0, 0);
    }

    float* dst = mat ? Q : P;
    int h = h0 + wave * 16 + lq * 4;
    f32x4 o = acc;
    if (!mat) o += *(const f32x4*)&b1[h];
    *(f32x4*)&dst[(size_t)(r0 + lc) * H_DIM + h] = o;
}

// ---------------- kernel 2: fused pairwise GEMM + LN + SiLU + W2 dot ----------------
// UNCHANGED from round 5 (measured best: 79.4 us).
// grid 2048 x 512 thr (8 waves). Block: 64 pairs x 512 H; K=256, 8 chunks.
// XCD-aware swizzle; atomic fire-and-forget output; setprio around MFMA;
// folded LN coefficients; f32x2 packed partials + epilogue.
__global__ __launch_bounds__(512, 4)
void main_kernel(const float* __restrict__ track, const float* __restrict__ det,
                 const __bf16* __restrict__ W1cc,
                 const float* __restrict__ P, const float* __restrict__ Q,
                 const float* __restrict__ sclT, const float* __restrict__ sclD,
                 const float* __restrict__ gamma, const float* __restrict__ beta,
                 const float* __restrict__ W2, const float* __restrict__ b2,
                 float* __restrict__ out) {
    __shared__ __align__(16) char SMEM[44032];
    __bf16* Ash  = (__bf16*)SMEM;                     // [0,32768)
    float*  LNr1 = (float*)(SMEM + 32768);            // [64][9]
    float*  LNr2 = (float*)(SMEM + 35072);            // [64][9]
    float*  AS   = (float*)(SMEM + 37376);            // [64]  a = rs
    float*  BS   = (float*)(SMEM + 37632);            // [64]  b = -mu*rs
    float*  Gs   = (float*)(SMEM + 37888);            // [512]
    float*  Bs   = (float*)(SMEM + 39936);            // [512]
    float*  Ws   = (float*)(SMEM + 41984);            // [512]

    int tid  = threadIdx.x;
    int lane = tid & 63;
    int wave = tid >> 6;
    int lq   = lane >> 4;
    int lc   = lane & 15;

    // ---- XCD-aware swizzle: XCD x owns a 4x8 (n-tile x m-tile) region per batch
    int i   = blockIdx.x;
    int xcd = i & 7;
    int t8  = (i >> 3) & 31;
    int b   = i >> 8;
    int n0  = ((xcd >> 1) * 4 + (t8 >> 3)) * 8;
    int m0  = ((xcd & 1) * 8 + (t8 & 7)) * 8;
    int gn  = b * 128 + n0;
    int gm  = b * 128 + m0;

    float b2v = b2[0];
    Gs[tid] = gamma[tid];
    Bs[tid] = beta[tid];
    Ws[tid] = W2[tid];

    // ---- W1c frags, chunk-0 prefetch
    const uint4* Wg = (const uint4*)W1cc;
    int hb = wave * 64 + lc;
    bf16x8 bwA[4], bwB[4];
#pragma unroll
    for (int ht = 0; ht < 4; ++ht)
        bwA[ht] = __builtin_bit_cast(bf16x8, Wg[(hb + ht * 16) * 4 + lq]);

    // ---- A-stage: |t*st - d*sd| straight from global (L2-hot) -> Ash
    int k0 = wave * 32 + lq * 8;
    int ml = lane & 7;
    float sd = sclD[gm + ml];
    const float* dr = det + (size_t)(gm + ml) * E_DIM + k0;
    float4 d0 = *(const float4*)dr;
    float4 d1 = *(const float4*)(dr + 4);
#pragma unroll
    for (int r = 0; r < 4; ++r) {
        int nl = r * 2 + (lc >> 3);
        float st = sclT[gn + nl];
        const float* tr = track + (size_t)(gn + nl) * E_DIM + k0;
        float4 t0 = *(const float4*)tr;
        float4 t1 = *(const float4*)(tr + 4);
        uint4 v;
        v.x = pkbf(fabsf(t0.x * st - d0.x * sd), fabsf(t0.y * st - d0.y * sd));
        v.y = pkbf(fabsf(t0.z * st - d0.z * sd), fabsf(t0.w * st - d0.w * sd));
        v.z = pkbf(fabsf(t1.x * st - d1.x * sd), fabsf(t1.y * st - d1.y * sd));
        v.w = pkbf(fabsf(t1.z * st - d1.z * sd), fabsf(t1.w * st - d1.w * sd));
        *(uint4*)&Ash[(size_t)(r * 512 + wave * 64 + lane) * 8] = v;
    }

    // ---- C-init: acc = P[n,h] + Q[m,h] (L2-resident) fused into MFMA C
    const float* Pb = P + (size_t)gn * H_DIM;
    const float* Qb = Q + (size_t)gm * H_DIM;
    f32x4 acc[4][4];
    {
        f32x4 qv[4];
#pragma unroll
        for (int ht = 0; ht < 4; ++ht)
            qv[ht] = *(const f32x4*)&Qb[(size_t)ml * H_DIM + wave * 64 + ht * 16 + lq * 4];
#pragma unroll
        for (int pt = 0; pt < 4; ++pt) {
            int n = pt * 2 + (lc >> 3);
#pragma unroll
            for (int ht = 0; ht < 4; ++ht) {
                f32x4 pv = *(const f32x4*)&Pb[(size_t)n * H_DIM + wave * 64 + ht * 16 + lq * 4];
                acc[pt][ht] = pv + qv[ht];
            }
        }
    }
    __syncthreads();

    // ---- K-loop: zero barriers; unroll-2 ping-pong dbuf; setprio around MFMA
#pragma unroll 2
    for (int c = 0; c < 8; ++c) {
        bf16x8* cur = (c & 1) ? bwB : bwA;
        bf16x8* nxt = (c & 1) ? bwA : bwB;
        int c1 = (c + 1) & 7;
#pragma unroll
        for (int ht = 0; ht < 4; ++ht)
            nxt[ht] = __builtin_bit_cast(bf16x8, Wg[c1 * 2048 + (hb + ht * 16) * 4 + lq]);
        __builtin_amdgcn_s_setprio(1);
#pragma unroll
        for (int pt = 0; pt < 4; ++pt) {
            bf16x8 af = *(const bf16x8*)&Ash[(size_t)((pt * 8 + c) * 64 + lane) * 8];
#pragma unroll
            for (int ht = 0; ht < 4; ++ht)
                acc[pt][ht] = __builtin_amdgcn_mfma_f32_16x16x32_bf16(cur[ht], af, acc[pt][ht], 0, 0, 0);
        }
        __builtin_amdgcn_s_setprio(0);
    }

    // ---- LN partials: packed f32x2 sums, 2 shuffles, two-stage LDS reduce
#pragma unroll
    for (int pt = 0; pt < 4; ++pt) {
        f32x2 s1v = (f32x2){0.f, 0.f}, s2v = (f32x2){0.f, 0.f};
#pragma unroll
        for (int ht = 0; ht < 4; ++ht) {
#pragma unroll
            for (int hf = 0; hf < 2; ++hf) {
                f32x2 v = (f32x2){acc[pt][ht][hf * 2], acc[pt][ht][hf * 2 + 1]};
                s1v += v;
                s2v += v * v;
            }
        }
        float s1 = s1v[0] + s1v[1];
        float s2 = s2v[0] + s2v[1];
        s1 += __shfl_xor(s1, 16); s2 += __shfl_xor(s2, 16);
        s1 += __shfl_xor(s1, 32); s2 += __shfl_xor(s2, 32);
        if (lq == 0) {
            LNr1[(pt * 16 + lc) * 9 + wave] = s1;
            LNr2[(pt * 16 + lc) * 9 + wave] = s2;
        }
    }
    __syncthreads();
    // ---- stats: all 512 threads (8 threads per pair, 3-level shuffle); folded coeffs
    {
        int p = tid >> 3, w = tid & 7;
        float s1 = LNr1[p * 9 + w];
        float s2 = LNr2[p * 9 + w];
        s1 += __shfl_xor(s1, 1); s2 += __shfl_xor(s2, 1);
        s1 += __shfl_xor(s1, 2); s2 += __shfl_xor(s2, 2);
        s1 += __shfl_xor(s1, 4); s2 += __shfl_xor(s2, 4);
        if (w == 0) {
            float mu  = s1 * (1.0f / 512.0f);
            float var = s2 * (1.0f / 512.0f) - mu * mu;
            float rs  = rsqrtf(var + 1e-5f);
            AS[p] = rs;
            BS[p] = -mu * rs;
        }
    }
    __syncthreads();

    // ---- epilogue: x = (v*a + b)*g + beta; SiLU; W2 dot; packed f32x2 chain
    float as[4], bs[4];
#pragma unroll
    for (int pt = 0; pt < 4; ++pt) { as[pt] = AS[pt * 16 + lc]; bs[pt] = BS[pt * 16 + lc]; }
    f32x2 cav[4];
#pragma unroll
    for (int pt = 0; pt < 4; ++pt) cav[pt] = (f32x2){0.f, 0.f};
#pragma unroll
    for (int ht = 0; ht < 4; ++ht) {
        int h = wave * 64 + ht * 16 + lq * 4;
        f32x4 g  = *(const f32x4*)&Gs[h];
        f32x4 bb = *(const f32x4*)&Bs[h];
        f32x4 w  = *(const f32x4*)&Ws[h];
#pragma unroll
        for (int pt = 0; pt < 4; ++pt) {
            f32x2 a2  = (f32x2){as[pt], as[pt]};
            f32x2 b2p = (f32x2){bs[pt], bs[pt]};
#pragma unroll
            for (int hf = 0; hf < 2; ++hf) {
                f32x2 v  = (f32x2){acc[pt][ht][hf * 2], acc[pt][ht][hf * 2 + 1]};
                f32x2 gg = (f32x2){g[hf * 2],  g[hf * 2 + 1]};
                f32x2 bv = (f32x2){bb[hf * 2], bb[hf * 2 + 1]};
                f32x2 wv = (f32x2){w[hf * 2],  w[hf * 2 + 1]};
                f32x2 x  = (v * a2 + b2p) * gg + bv;
                f32x2 xw = x * wv;
                f32x2 e, sg;
                e[0]  = __expf(-x[0]);
                e[1]  = __expf(-x[1]);
                sg[0] = __builtin_amdgcn_rcpf(1.0f + e[0]);
                sg[1] = __builtin_amdgcn_rcpf(1.0f + e[1]);
                cav[pt] += xw * sg;
            }
        }
    }
    // ---- output: per-wave partial -> fire-and-forget global atomic (no barrier,
    // no tail phase; block owns its 64 outputs exclusively, 8-way contention max)
#pragma unroll
    for (int pt = 0; pt < 4; ++pt) {
        float cg = cav[pt][0] + cav[pt][1];
        cg += __shfl_xor(cg, 16);
        cg += __shfl_xor(cg, 32);
        if (lq == 0) {
            if (wave == 0) cg += b2v;               // fold bias exactly once
            int n = pt * 2 + (lc >> 3);
            int m = lc & 7;
            atomicAdd(&out[(size_t)(gn + n) * 128 + m0 + m], cg);
        }
    }
}

extern "C" void kernel_launch(void* const* d_in, const int* in_sizes, int n_in,
                              void* d_out, int out_size, void* d_ws, size_t ws_size,
                              hipStream_t stream) {
    const float* track = (const float*)d_in[0];
    const float* det   = (const float*)d_in[1];
    const float* W1    = (const float*)d_in[2];
    const float* b1    = (const float*)d_in[3];
    const float* gamma = (const float*)d_in[4];
    const float* beta  = (const float*)d_in[5];
    const float* W2    = (const float*)d_in[6];
    const float* b2    = (const float*)d_in[7];
    float* out = (float*)d_out;

    char* ws = (char*)d_ws;
    float*  Pp   = (float*)(ws);                              // 2 MB (1024 x 512 f32)
    float*  Qp   = (float*)(ws + (2u << 20));                 // 2 MB
    __bf16* W1cc = (__bf16*)(ws + (4u << 20));                // 256 KB (mat 2 only)
    float*  sclT = (float*)(ws + (4u << 20) + (256u << 10));  // 4 KB
    float*  sclD = (float*)(ws + (4u << 20) + (264u << 10));  // 4 KB

    prep_kernel<<<512, 512, 0, stream>>>(track, det, W1, b1, Pp, Qp, W1cc, sclT, sclD, out);
    main_kernel<<<2048, 512, 0, stream>>>(track, det, W1cc, Pp, Qp, sclT, sclD,
                                          gamma, beta, W2, b2, out);
}